// Round 1
// baseline (235.581 us; speedup 1.0000x reference)
//
#include <hip/hip_runtime.h>
#include <math.h>

#define Bb      128
#define Nn      2000
#define Ee      2000
#define EMBED   256
#define HIDDEN  512
#define KDIM    512     // MFMA K (embedding part only; dist handled in epilogue)
#define BM      128     // edges per workgroup
#define NTHREADS 512    // 8 waves
#define NWG     2000    // 2000 * 128 = 256000 edges exactly

typedef __attribute__((ext_vector_type(8)))  short bf16x8;
typedef __attribute__((ext_vector_type(16))) float f32x16;

static __device__ __forceinline__ short f2bf(float f) {
  // round-to-nearest-even f32 -> bf16 bits (inputs are finite normals)
  unsigned u = __builtin_bit_cast(unsigned, f);
  u += 0x7fffu + ((u >> 16) & 1u);
  return (short)(u >> 16);
}

// ---------------- prep: W1 (513x512 f32 [k][n]) -> W1T bf16 [n][k], k<512 ----
__global__ void w1t_kernel(const float* __restrict__ W1, short* __restrict__ W1T) {
  __shared__ float t[32][33];
  const int kt = blockIdx.x & 15;   // k-tile
  const int nt = blockIdx.x >> 4;   // n-tile
  const int tx = threadIdx.x & 31;
  const int ty = threadIdx.x >> 5;  // 0..7
#pragma unroll
  for (int r = 0; r < 32; r += 8)
    t[ty + r][tx] = W1[(kt * 32 + ty + r) * HIDDEN + nt * 32 + tx];
  __syncthreads();
#pragma unroll
  for (int r = 0; r < 32; r += 8)
    W1T[(nt * 32 + ty + r) * KDIM + kt * 32 + tx] = f2bf(t[tx][ty + r]);
}

// ---------------- main fused kernel ----------------
__global__ __launch_bounds__(NTHREADS, 2)
void edge_kernel(const float* __restrict__ emb, const float* __restrict__ locs,
                 const int* __restrict__ edges, const int* __restrict__ dbias,
                 const float* __restrict__ W1, const float* __restrict__ b1,
                 const float* __restrict__ W2, const float* __restrict__ b2,
                 const short* __restrict__ W1T, float* __restrict__ out)
{
  // LDS: 36864 + 8192 + 512*4 + 4096 = 51200 B
  __shared__ short  A_lds[2][BM][72];   // feats tile, bf16, pad 64->72 (bank)
  __shared__ float4 ep_s[HIDDEN];       // {b1[n], W1[512][n], W2[n], 0}
  __shared__ float  dist_s[BM];
  __shared__ int    valid_s[BM];
  __shared__ int    ibase_s[BM];        // b*N + i   (row index into emb)
  __shared__ int    jbase_s[BM];
  __shared__ float  part_s[8][BM];      // per-wave logit partials

  const int tid = threadIdx.x;
  const int wg  = blockIdx.x;

  // ---- per-edge precompute ----
  if (tid < BM) {
    const int g  = wg * BM + tid;         // flat edge id = b*Ee + e
    const int b  = g / Ee;
    const int i0 = edges[2 * (size_t)g];
    const int j0 = edges[2 * (size_t)g + 1];
    const int valid = (i0 >= 0) && (j0 >= 0);
    const int ic = i0 < 0 ? 0 : i0;
    const int jc = j0 < 0 ? 0 : j0;
    const int ib = b * Nn + ic;
    const int jb = b * Nn + jc;
    ibase_s[tid] = ib;
    jbase_s[tid] = jb;
    valid_s[tid] = valid;
    const float dx = locs[2 * (size_t)ib]     - locs[2 * (size_t)jb];
    const float dy = locs[2 * (size_t)ib + 1] - locs[2 * (size_t)jb + 1];
    dist_s[tid] = sqrtf(dx * dx + dy * dy);
  }
  {
    // epilogue table: one entry per hidden n (512 threads -> one pass)
    const int n = tid;
    ep_s[n] = make_float4(b1[n], W1[(size_t)KDIM * HIDDEN + n], W2[n], 0.f);
  }
  __syncthreads();

  const int lane = tid & 63;
  const int wv   = tid >> 6;        // wave id 0..7 -> hidden slice [wv*64, wv*64+64)
  const int ln31 = lane & 31;
  const int kg   = lane >> 5;       // k-half for MFMA fragments

  // per-lane W1T bases (A operand rows = hidden n, k-contiguous)
  const short* pA0 = W1T + ((size_t)(wv * 64 + ln31) * KDIM) + kg * 8;
  const short* pA1 = pA0 + 32 * KDIM;

  // staging mapping: 4 lanes per edge, 64B (16 floats) per lane per chunk
  const int se = tid >> 2;          // edge 0..127
  const int sq = tid & 3;           // quarter of the 64-float chunk

  f32x16 acc[4][2];
#pragma unroll
  for (int et = 0; et < 4; ++et)
#pragma unroll
    for (int nt = 0; nt < 2; ++nt)
#pragma unroll
      for (int q = 0; q < 16; ++q) acc[et][nt][q] = 0.f;

  // ---- prologue: stage chunk 0 (emb_i, k 0..63) into buf 0 ----
  {
    const int rb = ibase_s[se];
    const float* p = emb + (size_t)rb * EMBED + sq * 16;
    float4 s0 = *(const float4*)(p);
    float4 s1 = *(const float4*)(p + 4);
    float4 s2 = *(const float4*)(p + 8);
    float4 s3 = *(const float4*)(p + 12);
    short* dst = &A_lds[0][se][sq * 16];
    bf16x8 v0, v1;
    v0[0]=f2bf(s0.x); v0[1]=f2bf(s0.y); v0[2]=f2bf(s0.z); v0[3]=f2bf(s0.w);
    v0[4]=f2bf(s1.x); v0[5]=f2bf(s1.y); v0[6]=f2bf(s1.z); v0[7]=f2bf(s1.w);
    v1[0]=f2bf(s2.x); v1[1]=f2bf(s2.y); v1[2]=f2bf(s2.z); v1[3]=f2bf(s2.w);
    v1[4]=f2bf(s3.x); v1[5]=f2bf(s3.y); v1[6]=f2bf(s3.z); v1[7]=f2bf(s3.w);
    *(bf16x8*)(dst)     = v0;
    *(bf16x8*)(dst + 8) = v1;
  }
  __syncthreads();

  // ---- K loop: 8 chunks of 64 ----
  for (int c = 0; c < 8; ++c) {
    // issue next chunk's gather loads early (hide HBM/L3 latency under MFMA)
    float4 s0, s1, s2, s3;
    if (c < 7) {
      const int cc = c + 1;
      const int rb = (cc < 4) ? ibase_s[se] : jbase_s[se];
      const float* p = emb + (size_t)rb * EMBED + (cc & 3) * 64 + sq * 16;
      s0 = *(const float4*)(p);
      s1 = *(const float4*)(p + 4);
      s2 = *(const float4*)(p + 8);
      s3 = *(const float4*)(p + 12);
    }

    const short* Ab = &A_lds[c & 1][0][0];
#pragma unroll
    for (int ks = 0; ks < 4; ++ks) {
      bf16x8 wa0 = *(const bf16x8*)(pA0 + c * 64 + ks * 16);
      bf16x8 wa1 = *(const bf16x8*)(pA1 + c * 64 + ks * 16);
#pragma unroll
      for (int et = 0; et < 4; ++et) {
        bf16x8 fb = *(const bf16x8*)(Ab + (et * 32 + ln31) * 72 + ks * 16 + kg * 8);
        acc[et][0] = __builtin_amdgcn_mfma_f32_32x32x16_bf16(wa0, fb, acc[et][0], 0, 0, 0);
        acc[et][1] = __builtin_amdgcn_mfma_f32_32x32x16_bf16(wa1, fb, acc[et][1], 0, 0, 0);
      }
    }

    if (c < 7) {
      short* dst = &A_lds[(c + 1) & 1][se][sq * 16];
      bf16x8 v0, v1;
      v0[0]=f2bf(s0.x); v0[1]=f2bf(s0.y); v0[2]=f2bf(s0.z); v0[3]=f2bf(s0.w);
      v0[4]=f2bf(s1.x); v0[5]=f2bf(s1.y); v0[6]=f2bf(s1.z); v0[7]=f2bf(s1.w);
      v1[0]=f2bf(s2.x); v1[1]=f2bf(s2.y); v1[2]=f2bf(s2.z); v1[3]=f2bf(s2.w);
      v1[4]=f2bf(s3.x); v1[5]=f2bf(s3.y); v1[6]=f2bf(s3.z); v1[7]=f2bf(s3.w);
      *(bf16x8*)(dst)     = v0;
      *(bf16x8*)(dst + 8) = v1;
    }
    __syncthreads();
  }

  // ---- epilogue: dist column + bias + relu + dot W2 (in-lane over n) ----
  const float d0 = dist_s[0 * 32 + ln31];
  const float d1 = dist_s[1 * 32 + ln31];
  const float d2 = dist_s[2 * 32 + ln31];
  const float d3 = dist_s[3 * 32 + ln31];
  float ps0 = 0.f, ps1 = 0.f, ps2 = 0.f, ps3 = 0.f;
#pragma unroll
  for (int nt = 0; nt < 2; ++nt) {
#pragma unroll
    for (int r = 0; r < 16; ++r) {
      const int n = wv * 64 + nt * 32 + (r & 3) + ((r >> 2) << 3) + (kg << 2);
      const float4 ep = ep_s[n];
      float p0 = acc[0][nt][r] + ep.x + d0 * ep.y;
      float p1 = acc[1][nt][r] + ep.x + d1 * ep.y;
      float p2 = acc[2][nt][r] + ep.x + d2 * ep.y;
      float p3 = acc[3][nt][r] + ep.x + d3 * ep.y;
      ps0 += fmaxf(p0, 0.f) * ep.z;
      ps1 += fmaxf(p1, 0.f) * ep.z;
      ps2 += fmaxf(p2, 0.f) * ep.z;
      ps3 += fmaxf(p3, 0.f) * ep.z;
    }
  }
  // fold the two k-half lane groups (rows differ by +4)
  ps0 += __shfl_xor(ps0, 32, 64);
  ps1 += __shfl_xor(ps1, 32, 64);
  ps2 += __shfl_xor(ps2, 32, 64);
  ps3 += __shfl_xor(ps3, 32, 64);
  if (lane < 32) {
    part_s[wv][0 * 32 + ln31] = ps0;
    part_s[wv][1 * 32 + ln31] = ps1;
    part_s[wv][2 * 32 + ln31] = ps2;
    part_s[wv][3 * 32 + ln31] = ps3;
  }
  __syncthreads();

  if (tid < BM) {
    float s = part_s[0][tid];
#pragma unroll
    for (int w = 1; w < 8; ++w) s += part_s[w][tid];
    float logit = s + b2[0] + (float)dbias[0];
    if (!valid_s[tid]) logit = -__builtin_inff();
    out[(size_t)wg * BM + tid] = logit;
  }
}

extern "C" void kernel_launch(void* const* d_in, const int* in_sizes, int n_in,
                              void* d_out, int out_size, void* d_ws, size_t ws_size,
                              hipStream_t stream) {
  const float* emb   = (const float*)d_in[0];
  const float* locs  = (const float*)d_in[1];
  const int*   edges = (const int*)d_in[2];
  const int*   dbias = (const int*)d_in[3];
  const float* W1    = (const float*)d_in[4];
  const float* b1    = (const float*)d_in[5];
  const float* W2    = (const float*)d_in[6];
  const float* b2    = (const float*)d_in[7];
  float*       out   = (float*)d_out;
  short*       W1T   = (short*)d_ws;   // 512*512*2 = 512 KiB

  w1t_kernel<<<dim3(256), dim3(256), 0, stream>>>(W1, W1T);
  edge_kernel<<<dim3(NWG), dim3(NTHREADS), 0, stream>>>(
      emb, locs, edges, dbias, W1, b1, W2, b2, (const short*)W1T, out);
}